// Round 3
// baseline (338.853 us; speedup 1.0000x reference)
//
#include <hip/hip_runtime.h>

// DynamicFilter: out[b,c,h,w] = sum_p (y[c*9+p] + bias[c*9+p]) * x[b,c,h+dh,w+dw]
//   y[o] = sum_c' x[b,c',h,w] * W[o,c']   (GEMM M=65536, N=2304, K=256, bf16 MFMA)
// B=4, C=256, H=W=128, 9 taps.
// R3: A fragments in registers (afr[16], mi=2, block = 128 px = full row) ->
// B-frag LDS reads halved, A LDS region gone, LDS 36864 B -> 3 blocks/CU.
// xtrans is now a pure global permute (no LDS) emitting xT2 tile-major so
// dfgemm's A loads are 16 coalesced 1-KB dwordx4 reads.

typedef __attribute__((ext_vector_type(8))) short bf16x8;   // 8 bf16 = 4 VGPRs
typedef __attribute__((ext_vector_type(4))) float f32x4;    // MFMA 16x16 acc

__device__ __forceinline__ unsigned int f2bf(float f) {
    unsigned int u = __float_as_uint(f);
    return (u + 0x7fffu + ((u >> 16) & 1u)) >> 16;   // RNE
}
__device__ __forceinline__ unsigned int pack2(float a, float b) {
    return f2bf(a) | (f2bf(b) << 16);
}

// ---------------------------------------------------------------------------
// Kernel 1: W (2304x256 fp32) -> Wb bf16, k-half-major:
//   Wb[kh][o][16 groups of 8 k], gs = ((gh&7)^(o&7)) | (gh&8)   (unchanged R2)
// ---------------------------------------------------------------------------
__global__ __launch_bounds__(256) void wconv_kernel(const float* __restrict__ W,
                                                    unsigned char* __restrict__ Wb) {
    int idx = blockIdx.x * 256 + threadIdx.x;    // 73728 = 2304 * 32 groups
    int o = idx >> 5, g = idx & 31;
    const float4* src = (const float4*)(W + ((size_t)o << 8) + ((size_t)g << 3));
    float4 v0 = src[0], v1 = src[1];
    uint4 pk;
    pk.x = pack2(v0.x, v0.y); pk.y = pack2(v0.z, v0.w);
    pk.z = pack2(v1.x, v1.y); pk.w = pack2(v1.z, v1.w);
    int kh = g >> 4, gh = g & 15;
    int gs = ((gh & 7) ^ (o & 7)) | (gh & 8);
    size_t dst = (size_t)kh * 589824 + (size_t)o * 256 + ((size_t)gs << 4);
    *(uint4*)(Wb + dst) = pk;
}

// ---------------------------------------------------------------------------
// Kernel 2: x -> xT2, tile-major: per 16-px tile (8192 B):
//   addr = tile*8192 + (c>>5)*1024 + ((c>>3)&3)*256 + (px&15)*16 + (c&7)*2
// so dfgemm A-frag load (kh,s) is a contiguous 1 KB: tile + gg*1024 + lane*16.
// Pure global permute: 64 coalesced dword loads + 8 coalesced uint4 stores/thr.
// ---------------------------------------------------------------------------
__global__ __launch_bounds__(256) void xtrans_kernel(const float* __restrict__ x,
                                                     unsigned char* __restrict__ xT2) {
    const int t = threadIdx.x;
    const int m = t & 63, kq = t >> 6;           // m = pixel-in-block, kq 0..3
    const int pix0 = blockIdx.x << 6;            // 64 px per block
    const int b = pix0 >> 14, hw0 = pix0 & 16383;
    const float* src = x + ((size_t)b << 22) + hw0 + m;
    unsigned char* dstT = xT2 + ((size_t)pix0 << 9)
                        + ((m >> 4) * 8192) + ((m & 15) << 4);
    #pragma unroll
    for (int j = 0; j < 8; ++j) {
        const int g = (j << 2) + kq;             // channel group 0..31 (8 ch)
        float v[8];
        #pragma unroll
        for (int e = 0; e < 8; ++e)
            v[e] = src[(size_t)((g << 3) + e) << 14];   // 256 B coalesced/instr
        uint4 pk;
        pk.x = pack2(v[0], v[1]); pk.y = pack2(v[2], v[3]);
        pk.z = pack2(v[4], v[5]); pk.w = pack2(v[6], v[7]);
        *(uint4*)(dstT + ((g >> 2) << 10) + ((g & 3) << 8)) = pk;  // 256-B segs
    }
}

// ---------------------------------------------------------------------------
// Kernel 3: fused GEMM + epilogue. 512 blocks x 256 thr; block = 128 px (one
// image row). A frags in regs: afr[mi*8 + kh*4 + s] (64 VGPR). Wave tile
// 32 px x 144 out, acc[2][9]. 16 chunks of 144 outs; per chunk 2 stagings of
// 36864 B (global_load_lds x16). Epilogue per mi-half: Y [out][px16] fp32 in
// the B region (9216 B/wave), b128 writes; patches fp32 from x. LDS 36864 ->
// 3 blocks/CU with launch_bounds(256,3).
// ---------------------------------------------------------------------------
__global__ __launch_bounds__(256, 3) void dfgemm_kernel(
        const unsigned char* __restrict__ xT2, const unsigned char* __restrict__ Wb,
        const float* __restrict__ x, const float* __restrict__ bias,
        float* __restrict__ out) {
    __shared__ __align__(16) unsigned char smem[36864];

    const int t = threadIdx.x;
    const int lane = t & 63, wv = t >> 6;
    const int quad = lane >> 4, lrow = lane & 15;
    const int swz = lrow & 7;

    const int pix0 = blockIdx.x << 7;            // 128 px = full row
    const int b = blockIdx.x >> 7;               // image 0..3
    const int h = blockIdx.x & 127;              // row

    // ---- A fragments -> registers: 16 coalesced 1-KB loads from xT2 ----
    bf16x8 afr[16];                               // [mi*8 + kh*4 + s]
    #pragma unroll
    for (int mi = 0; mi < 2; ++mi) {
        const unsigned char* tb = xT2
            + ((size_t)(pix0 + (wv << 5) + (mi << 4)) << 9) + (lane << 4);
        #pragma unroll
        for (int gg = 0; gg < 8; ++gg)
            afr[(mi << 3) + gg] = *(const bf16x8*)(tb + (gg << 10));
    }

    #pragma unroll 1
    for (int chunk = 0; chunk < 16; ++chunk) {
        f32x4 acc[2][9];
        const f32x4 zero = {0.f, 0.f, 0.f, 0.f};
        #pragma unroll
        for (int mi = 0; mi < 2; ++mi)
            #pragma unroll
            for (int ni = 0; ni < 9; ++ni) acc[mi][ni] = zero;

        #pragma unroll 1
        for (int kh = 0; kh < 2; ++kh) {
            __syncthreads();   // prior B-frag / Y readers done before restage
            {   // wave wv stages bytes [wv*9216, +9216) of the 36864-B B tile
                const unsigned char* bs = Wb + (size_t)kh * 589824
                                        + (size_t)chunk * 36864 + wv * 9216 + (lane << 4);
                unsigned char* bd = smem + wv * 9216;
                #pragma unroll
                for (int c = 0; c < 9; ++c)
                    __builtin_amdgcn_global_load_lds(
                        (const __attribute__((address_space(1))) void*)(bs + c * 1024),
                        (__attribute__((address_space(3))) void*)(bd + c * 1024), 16, 0, 0);
            }
            __builtin_amdgcn_s_waitcnt(0);
            __syncthreads();

            #pragma unroll
            for (int s = 0; s < 4; ++s) {
                const int gb = (s << 2) + quad;              // B group 0..15
                const bf16x8 a0 = afr[(kh << 2) + s];
                const bf16x8 a1 = afr[8 + (kh << 2) + s];
                #pragma unroll
                for (int ni = 0; ni < 9; ++ni) {
                    const bf16x8 bq = *(const bf16x8*)(
                        smem + (((ni << 4) + lrow) << 8) + ((gb ^ swz) << 4));
                    acc[0][ni] = __builtin_amdgcn_mfma_f32_16x16x32_bf16(a0, bq, acc[0][ni], 0, 0, 0);
                    acc[1][ni] = __builtin_amdgcn_mfma_f32_16x16x32_bf16(a1, bq, acc[1][ni], 0, 0, 0);
                }
            }
        }
        __syncthreads();   // all waves' B-frag reads done; region reusable as Y

        // ---- epilogue: per-wave Y [144 out][16 px] fp32 (9216 B), per half ----
        float* Y = (float*)(smem + wv * 9216);
        #pragma unroll
        for (int half = 0; half < 2; ++half) {
            #pragma unroll
            for (int ni = 0; ni < 9; ++ni)
                *(f32x4*)(Y + (((ni << 4) + lrow) << 4) + (quad << 2)) = acc[half][ni];
            __builtin_amdgcn_s_waitcnt(0);   // wave-local LDS RAW

            const int w = (wv << 5) + (half << 4) + lrow;    // this lane's pixel
            #pragma unroll
            for (int it = 0; it < 4; ++it) {
                const int cgl = (it << 2) + quad;            // 0..15
                const int cg = (chunk << 4) + cgl;           // channel 0..255
                const float* ycol = Y + cgl * 144 + lrow;    // (cgl*9+p)*16 + lrow
                const float* bp = bias + cg * 9;
                const float* xc = x + ((size_t)((b << 8) + cg) << 14);
                float sum = 0.f;
                #pragma unroll
                for (int p = 0; p < 9; ++p) {
                    const int hh = h + p / 3 - 1, ww = w + p % 3 - 1;
                    float xv = 0.f;
                    if ((unsigned)hh < 128u && (unsigned)ww < 128u)
                        xv = xc[(hh << 7) + ww];             // fp32 patch
                    sum += (ycol[p << 4] + bp[p]) * xv;
                }
                out[((size_t)((b << 8) + cg) << 14) + (h << 7) + w] = sum;
            }
        }
    }
}

extern "C" void kernel_launch(void* const* d_in, const int* in_sizes, int n_in,
                              void* d_out, int out_size, void* d_ws, size_t ws_size,
                              hipStream_t stream) {
    const float* x    = (const float*)d_in[0];   // 4*256*128*128
    const float* W    = (const float*)d_in[1];   // 2304*256
    const float* bias = (const float*)d_in[2];   // 2304
    float* out = (float*)d_out;

    unsigned char* xT2 = (unsigned char*)d_ws;                 // 33,554,432 B
    unsigned char* Wb  = (unsigned char*)d_ws + 33554432;      //  1,179,648 B

    wconv_kernel<<<288, 256, 0, stream>>>(W, Wb);
    xtrans_kernel<<<1024, 256, 0, stream>>>(x, xT2);
    dfgemm_kernel<<<512, 256, 0, stream>>>(xT2, Wb, x, bias, out);
}

// Round 4
// 299.473 us; speedup vs baseline: 1.1315x; 1.1315x over previous
//
#include <hip/hip_runtime.h>

// DynamicFilter: out[b,c,h,w] = sum_p (y[c*9+p] + bias[c*9+p]) * x[b,c,h+dh,w+dw]
//   y[o] = sum_c' x[b,c',h,w] * W[o,c']   (GEMM M=65536, N=2304, K=256, bf16 MFMA)
// B=4, C=256, H=W=128, 9 taps.
// R4: (a) launch_bounds(256,2) — R3's (256,3) spilled afr[16] -> +0.5 GB scratch
// traffic; (b) xtrans kernel eliminated — A fragments loaded directly from x
// (4x64B segments/instr, each line touched once) and converted in-register;
// (c) Y pitch 16 -> 20 dwords: b128 epilogue writes now cover all 32 banks per
// 8-lane group (was 4-way conflict). LDS 46080 B -> 2 blocks/CU.

typedef __attribute__((ext_vector_type(8))) short bf16x8;   // 8 bf16 = 4 VGPRs
typedef __attribute__((ext_vector_type(4))) float f32x4;    // MFMA 16x16 acc

__device__ __forceinline__ unsigned int f2bf(float f) {
    unsigned int u = __float_as_uint(f);
    return (u + 0x7fffu + ((u >> 16) & 1u)) >> 16;   // RNE
}
__device__ __forceinline__ unsigned int pack2(float a, float b) {
    return f2bf(a) | (f2bf(b) << 16);
}

// ---------------------------------------------------------------------------
// Kernel 1: W (2304x256 fp32) -> Wb bf16, k-half-major:
//   Wb[kh][o][16 groups of 8 k], gs = ((gh&7)^(o&7)) | (gh&8)
// ---------------------------------------------------------------------------
__global__ __launch_bounds__(256) void wconv_kernel(const float* __restrict__ W,
                                                    unsigned char* __restrict__ Wb) {
    int idx = blockIdx.x * 256 + threadIdx.x;    // 73728 = 2304 * 32 groups
    int o = idx >> 5, g = idx & 31;
    const float4* src = (const float4*)(W + ((size_t)o << 8) + ((size_t)g << 3));
    float4 v0 = src[0], v1 = src[1];
    uint4 pk;
    pk.x = pack2(v0.x, v0.y); pk.y = pack2(v0.z, v0.w);
    pk.z = pack2(v1.x, v1.y); pk.w = pack2(v1.z, v1.w);
    int kh = g >> 4, gh = g & 15;
    int gs = ((gh & 7) ^ (o & 7)) | (gh & 8);
    size_t dst = (size_t)kh * 589824 + (size_t)o * 256 + ((size_t)gs << 4);
    *(uint4*)(Wb + dst) = pk;
}

// ---------------------------------------------------------------------------
// Kernel 2: fused GEMM + epilogue. 512 blocks x 256 thr; block = 128 px (one
// image row of one image). A frags loaded straight from x into afr[16]
// (64 VGPR, persistent; launch_bounds(256,2) => no spill). Wave tile
// 32 px x 144 out, acc[2][9] (72 AGPR). 16 chunks of 144 outs; per chunk 2
// stagings of 36864 B Wb tile (global_load_lds x16). Epilogue: per-wave
// Y [144 out][20-dword pitch] fp32 (11520 B) aliased over B region; b128
// writes conflict-free; patches fp32 from x.
// ---------------------------------------------------------------------------
__global__ __launch_bounds__(256, 2) void dfgemm_kernel(
        const unsigned char* __restrict__ Wb, const float* __restrict__ x,
        const float* __restrict__ bias, float* __restrict__ out) {
    __shared__ __align__(16) unsigned char smem[46080];   // B tile 36864 | Y 4x11520

    const int t = threadIdx.x;
    const int lane = t & 63, wv = t >> 6;
    const int quad = lane >> 4, lrow = lane & 15;
    const int swz = lrow & 7;

    const int b = blockIdx.x >> 7;               // image 0..3
    const int h = blockIdx.x & 127;              // row

    // ---- A fragments direct from x: afr[mi*8+gg][j] = bf16(x[b, gg*32+quad*8+j, h, w]) ----
    bf16x8 afr[16];
    {
        const float* xrow = x + ((size_t)b << 22) + (h << 7);
        #pragma unroll
        for (int mi = 0; mi < 2; ++mi) {
            const int w = (wv << 5) + (mi << 4) + lrow;
            #pragma unroll
            for (int gg = 0; gg < 8; ++gg) {
                const float* p = xrow + ((size_t)((gg << 5) + (quad << 3)) << 14) + w;
                float v[8];
                #pragma unroll
                for (int e = 0; e < 8; ++e) v[e] = p[(size_t)e << 14];
                uint4 pk;
                pk.x = pack2(v[0], v[1]); pk.y = pack2(v[2], v[3]);
                pk.z = pack2(v[4], v[5]); pk.w = pack2(v[6], v[7]);
                afr[(mi << 3) + gg] = *(const bf16x8*)&pk;
            }
        }
    }

    #pragma unroll 1
    for (int chunk = 0; chunk < 16; ++chunk) {
        f32x4 acc[2][9];
        const f32x4 zero = {0.f, 0.f, 0.f, 0.f};
        #pragma unroll
        for (int mi = 0; mi < 2; ++mi)
            #pragma unroll
            for (int ni = 0; ni < 9; ++ni) acc[mi][ni] = zero;

        #pragma unroll 1
        for (int kh = 0; kh < 2; ++kh) {
            __syncthreads();   // prior B-frag / Y readers done before restage
            {   // wave wv stages bytes [wv*9216, +9216) of the 36864-B B tile
                const unsigned char* bs = Wb + (size_t)kh * 589824
                                        + (size_t)chunk * 36864 + wv * 9216 + (lane << 4);
                unsigned char* bd = smem + wv * 9216;
                #pragma unroll
                for (int c = 0; c < 9; ++c)
                    __builtin_amdgcn_global_load_lds(
                        (const __attribute__((address_space(1))) void*)(bs + c * 1024),
                        (__attribute__((address_space(3))) void*)(bd + c * 1024), 16, 0, 0);
            }
            __builtin_amdgcn_s_waitcnt(0);
            __syncthreads();

            #pragma unroll
            for (int s = 0; s < 4; ++s) {
                const int gb = (s << 2) + quad;              // B group 0..15
                const bf16x8 a0 = afr[(kh << 2) + s];
                const bf16x8 a1 = afr[8 + (kh << 2) + s];
                #pragma unroll
                for (int ni = 0; ni < 9; ++ni) {
                    const bf16x8 bq = *(const bf16x8*)(
                        smem + (((ni << 4) + lrow) << 8) + ((gb ^ swz) << 4));
                    acc[0][ni] = __builtin_amdgcn_mfma_f32_16x16x32_bf16(a0, bq, acc[0][ni], 0, 0, 0);
                    acc[1][ni] = __builtin_amdgcn_mfma_f32_16x16x32_bf16(a1, bq, acc[1][ni], 0, 0, 0);
                }
            }
        }
        __syncthreads();   // all waves' B-frag reads done; region reusable as Y

        // ---- epilogue: per-wave Y [144 out][pitch 20 dwords] fp32 (11520 B) ----
        float* Y = (float*)(smem + wv * 11520);
        #pragma unroll
        for (int half = 0; half < 2; ++half) {
            #pragma unroll
            for (int ni = 0; ni < 9; ++ni)
                *(f32x4*)(Y + ((ni << 4) + lrow) * 20 + (quad << 2)) = acc[half][ni];
            __builtin_amdgcn_s_waitcnt(0);   // wave-local LDS RAW

            const int w = (wv << 5) + (half << 4) + lrow;    // this lane's pixel
            #pragma unroll
            for (int it = 0; it < 4; ++it) {
                const int cgl = (it << 2) + quad;            // 0..15
                const int cg = (chunk << 4) + cgl;           // channel 0..255
                const float* yrow = Y + cgl * 180 + lrow;    // (cgl*9+p)*20 + lrow
                const float* bp = bias + cg * 9;
                const float* xc = x + ((size_t)((b << 8) + cg) << 14);
                float sum = 0.f;
                #pragma unroll
                for (int p = 0; p < 9; ++p) {
                    const int hh = h + p / 3 - 1, ww = w + p % 3 - 1;
                    float xv = 0.f;
                    if ((unsigned)hh < 128u && (unsigned)ww < 128u)
                        xv = xc[(hh << 7) + ww];             // fp32 patch
                    sum += (yrow[p * 20] + bp[p]) * xv;
                }
                out[((size_t)((b << 8) + cg) << 14) + (h << 7) + w] = sum;
            }
        }
    }
}

extern "C" void kernel_launch(void* const* d_in, const int* in_sizes, int n_in,
                              void* d_out, int out_size, void* d_ws, size_t ws_size,
                              hipStream_t stream) {
    const float* x    = (const float*)d_in[0];   // 4*256*128*128
    const float* W    = (const float*)d_in[1];   // 2304*256
    const float* bias = (const float*)d_in[2];   // 2304
    float* out = (float*)d_out;

    unsigned char* Wb = (unsigned char*)d_ws;    // 1,179,648 B

    wconv_kernel<<<288, 256, 0, stream>>>(W, Wb);
    dfgemm_kernel<<<512, 256, 0, stream>>>(Wb, x, bias, out);
}